// Round 9
// baseline (719.820 us; speedup 1.0000x reference)
//
#include <hip/hip_runtime.h>
#include <hip/hip_fp16.h>
#include <math.h>

#define NNODES 100000
#define NEDGES 3200000
#define NFEAT  512
#define NHID   256
#define NCLASS 40
#define DPB    128                       // dsts per bucket
#define NBUCK  782                       // ceil(NNODES / DPB)
#define NSLICE 16                        // src slices of 8192 rows (4 MB of h0)
#define TILE   16384                     // edges per bin block
#define NTILE  196                       // ceil(NEDGES / TILE)

typedef _Float16 half8 __attribute__((ext_vector_type(8)));
typedef _Float16 half4 __attribute__((ext_vector_type(4)));
typedef float  f32x4  __attribute__((ext_vector_type(4)));

// ============ W1 transpose + fp16 convert: W1[512][256] -> W1T[256][512] ====
__global__ __launch_bounds__(256) void w1_f16_kernel(
    const float* __restrict__ W1, _Float16* __restrict__ W1T)
{
    const int i = blockIdx.x * 256 + threadIdx.x;     // 131072 total
    if (i >= NFEAT * NHID) return;
    const int k = i >> 8;        // row of W1 (K)
    const int n = i & 255;       // col of W1 (N)
    W1T[n * NFEAT + k] = (_Float16)W1[i];
}

// ============ GEMM1 via f16 MFMA (single pass): h0 = fp16(x @ W1 + b1) ======
__global__ __launch_bounds__(256) void gemm1_f16_kernel(
    const float* __restrict__ x, const _Float16* __restrict__ Bt,
    const float* __restrict__ b1, _Float16* __restrict__ h0)
{
    __shared__ __align__(16) _Float16 As[64 * 40];   // [row][k], pad 40
    const int t = threadIdx.x;
    const int lane = t & 63;
    const int w = t >> 6;
    const int row0 = blockIdx.x * 64;
    const int wn0 = w * 64;
    const int fr = lane & 15;
    const int fq = lane >> 4;
    const int srow = t >> 2;
    const int skq  = (t & 3) * 8;
    const int grow = row0 + srow;
    const float* xp = x + (size_t)grow * NFEAT + skq;
    _Float16* ap = &As[srow * 40 + skq];

    f32x4 acc[4][4] = {};

    for (int k0 = 0; k0 < NFEAT; k0 += 32) {
        half8 hv;
        if (grow < NNODES) {
            const float4 u0 = *(const float4*)(xp + k0);
            const float4 u1 = *(const float4*)(xp + k0 + 4);
            hv[0] = (_Float16)u0.x; hv[1] = (_Float16)u0.y;
            hv[2] = (_Float16)u0.z; hv[3] = (_Float16)u0.w;
            hv[4] = (_Float16)u1.x; hv[5] = (_Float16)u1.y;
            hv[6] = (_Float16)u1.z; hv[7] = (_Float16)u1.w;
        } else {
            #pragma unroll
            for (int j = 0; j < 8; ++j) hv[j] = (_Float16)0.f;
        }
        __syncthreads();
        *(half8*)ap = hv;
        __syncthreads();

        half8 a_f[4];
        #pragma unroll
        for (int mt = 0; mt < 4; ++mt)
            a_f[mt] = *(const half8*)&As[(mt * 16 + fr) * 40 + fq * 8];
        half8 b_f[4];
        #pragma unroll
        for (int nt = 0; nt < 4; ++nt) {
            const int n = wn0 + nt * 16 + fr;
            b_f[nt] = *(const half8*)(Bt + (size_t)n * NFEAT + k0 + fq * 8);
        }
        #pragma unroll
        for (int mt = 0; mt < 4; ++mt)
            #pragma unroll
            for (int nt = 0; nt < 4; ++nt)
                acc[mt][nt] = __builtin_amdgcn_mfma_f32_16x16x32_f16(
                    a_f[mt], b_f[nt], acc[mt][nt], 0, 0, 0);
    }
    #pragma unroll
    for (int mt = 0; mt < 4; ++mt)
        #pragma unroll
        for (int nt = 0; nt < 4; ++nt) {
            const int c = wn0 + nt * 16 + fr;
            const float bias = b1[c];
            const int r0 = row0 + mt * 16 + fq * 4;
            #pragma unroll
            for (int r = 0; r < 4; ++r) {
                const int row = r0 + r;
                if (row < NNODES)
                    h0[(size_t)row * NHID + c] = (_Float16)(acc[mt][nt][r] + bias);
            }
        }
}

// ============ GEMM2: h2 = fp16(relu'd fp16 h1 @ W2 + b2) ====================
__global__ __launch_bounds__(256) void gemm2_kernel(
    const _Float16* __restrict__ h1, const float* __restrict__ W2,
    const float* __restrict__ b2, _Float16* __restrict__ h2)
{
    __shared__ float Bs[NHID * NCLASS];
    __shared__ float As[64][33];
    const int t = threadIdx.x;
    const int row0 = blockIdx.x * 64;
    for (int i = t; i < NHID * NCLASS; i += 256) Bs[i] = W2[i];
    const int r  = t & 63;
    const int cg = (t >> 6) * 10;
    const int am = t >> 2, ak = (t & 3) * 8;
    float acc[10] = {};
    for (int k0 = 0; k0 < NHID; k0 += 32) {
        __syncthreads();
        half8 hv;
        #pragma unroll
        for (int j = 0; j < 8; ++j) hv[j] = (_Float16)0.f;
        const int arow = row0 + am;
        if (arow < NNODES)
            hv = *(const half8*)(h1 + (size_t)arow * NHID + k0 + ak);
        #pragma unroll
        for (int j = 0; j < 8; ++j)
            As[am][ak + j] = (float)hv[j];
        __syncthreads();
        #pragma unroll
        for (int k = 0; k < 32; ++k) {
            const float a = As[r][k];
            #pragma unroll
            for (int j = 0; j < 10; ++j)
                acc[j] += a * Bs[(k0 + k) * NCLASS + cg + j];
        }
    }
    const int arow = row0 + r;
    if (arow < NNODES) {
        #pragma unroll
        for (int j = 0; j < 10; ++j)
            h2[(size_t)arow * NCLASS + cg + j] = (_Float16)(acc[j] + b2[cg + j]);
    }
}

// ============ CSR build: two-level binned counting sort =====================
__global__ __launch_bounds__(256) void csr_init_kernel(
    int* __restrict__ bhist, int* __restrict__ rowptr)
{
    const int i = blockIdx.x * 256 + threadIdx.x;
    if (i < NBUCK) bhist[i] = 0;
    if (i == 0) rowptr[NNODES] = NEDGES;
}

__global__ __launch_bounds__(256) void bin_count_kernel(
    const int* __restrict__ ei, int* __restrict__ bhist)
{
    __shared__ int h[NBUCK];
    const int t = threadIdx.x;
    for (int i = t; i < NBUCK; i += 256) h[i] = 0;
    __syncthreads();
    const int base = blockIdx.x * TILE;
    #pragma unroll 1
    for (int it = 0; it < TILE / 1024; ++it) {
        const int e = base + it * 1024 + t * 4;
        if (e + 3 < NEDGES) {
            const int4 d = *(const int4*)(ei + e);
            atomicAdd(&h[d.x >> 7], 1);
            atomicAdd(&h[d.y >> 7], 1);
            atomicAdd(&h[d.z >> 7], 1);
            atomicAdd(&h[d.w >> 7], 1);
        } else {
            for (int j = e; j < NEDGES; ++j) atomicAdd(&h[ei[j] >> 7], 1);
        }
    }
    __syncthreads();
    for (int i = t; i < NBUCK; i += 256)
        if (h[i]) atomicAdd(&bhist[i], h[i]);
}

__global__ __launch_bounds__(1024) void bucket_scan_kernel(
    const int* __restrict__ bhist, int* __restrict__ bbase, int* __restrict__ bcur)
{
    __shared__ int s[1024];
    const int t = threadIdx.x;
    const int v = (t < NBUCK) ? bhist[t] : 0;
    s[t] = v;
    __syncthreads();
    for (int o = 1; o < 1024; o <<= 1) {
        const int u = (t >= o) ? s[t - o] : 0;
        __syncthreads();
        s[t] += u;
        __syncthreads();
    }
    if (t < NBUCK) { bbase[t] = s[t] - v; bcur[t] = s[t] - v; }
    if (t == 1023) bbase[NBUCK] = s[1023];
}

// packed: .x = (local_dst << 17) | src
__global__ __launch_bounds__(256) void bin_scatter_kernel(
    const int* __restrict__ ei, const float* __restrict__ ew,
    int* __restrict__ bcur, int2* __restrict__ binned)
{
    __shared__ int h[NBUCK];
    __shared__ int cur[NBUCK];
    const int t = threadIdx.x;
    for (int i = t; i < NBUCK; i += 256) h[i] = 0;
    __syncthreads();
    const int base = blockIdx.x * TILE;
    #pragma unroll 1
    for (int it = 0; it < TILE / 1024; ++it) {
        const int e = base + it * 1024 + t * 4;
        if (e + 3 < NEDGES) {
            const int4 d = *(const int4*)(ei + e);
            atomicAdd(&h[d.x >> 7], 1);
            atomicAdd(&h[d.y >> 7], 1);
            atomicAdd(&h[d.z >> 7], 1);
            atomicAdd(&h[d.w >> 7], 1);
        } else {
            for (int j = e; j < NEDGES; ++j) atomicAdd(&h[ei[j] >> 7], 1);
        }
    }
    __syncthreads();
    for (int i = t; i < NBUCK; i += 256)
        if (h[i]) cur[i] = atomicAdd(&bcur[i], h[i]);
    __syncthreads();
    #pragma unroll 1
    for (int it = 0; it < TILE / 1024; ++it) {
        const int e = base + it * 1024 + t * 4;
        if (e + 3 < NEDGES) {
            const int4   d = *(const int4*)(ei + e);
            const int4   s = *(const int4*)(ei + NEDGES + e);
            const float4 w = *(const float4*)(ew + e);
            int p0 = atomicAdd(&cur[d.x >> 7], 1);
            int p1 = atomicAdd(&cur[d.y >> 7], 1);
            int p2 = atomicAdd(&cur[d.z >> 7], 1);
            int p3 = atomicAdd(&cur[d.w >> 7], 1);
            binned[p0] = make_int2(((d.x & 127) << 17) | s.x, __float_as_int(w.x));
            binned[p1] = make_int2(((d.y & 127) << 17) | s.y, __float_as_int(w.y));
            binned[p2] = make_int2(((d.z & 127) << 17) | s.z, __float_as_int(w.z));
            binned[p3] = make_int2(((d.w & 127) << 17) | s.w, __float_as_int(w.w));
        } else {
            for (int j = e; j < NEDGES; ++j) {
                const int dj = ei[j];
                const int p = atomicAdd(&cur[dj >> 7], 1);
                binned[p] = make_int2(((dj & 127) << 17) | ei[NEDGES + j],
                                      __float_as_int(ew[j]));
            }
        }
    }
}

// one block per bucket: counting-sort by (local_dst, src>>13) -> pairs + rowptr
// => each dst's segment is ordered by 4MB src slice (per-XCD L2 locality)
__global__ __launch_bounds__(256) void regroup_kernel(
    const int* __restrict__ bbase, const int2* __restrict__ binned,
    int* __restrict__ rowptr, int2* __restrict__ pairs)
{
    __shared__ int cnt[DPB * NSLICE];    // 2048 keys
    __shared__ int ss[256];
    const int b = blockIdx.x;
    const int t = threadIdx.x;
    const int d0 = b * DPB;
    const int nd = (NNODES - d0 < DPB) ? (NNODES - d0) : DPB;
    #pragma unroll
    for (int j = 0; j < (DPB * NSLICE) / 256; ++j) cnt[j * 256 + t] = 0;
    __syncthreads();
    const int lo = bbase[b], hiE = bbase[b + 1];
    for (int idx = lo + t; idx < hiE; idx += 256) {
        const int xv = binned[idx].x;
        const int key = ((xv >> 17) << 4) | ((xv & 0x1FFFF) >> 13);
        atomicAdd(&cnt[key], 1);
    }
    __syncthreads();
    // exclusive scan over 2048 keys; thread t owns [8t, 8t+8)
    int v[8];
    int tsum = 0;
    #pragma unroll
    for (int j = 0; j < 8; ++j) { v[j] = cnt[8 * t + j]; tsum += v[j]; }
    ss[t] = tsum;
    __syncthreads();
    for (int o = 1; o < 256; o <<= 1) {
        const int u = (t >= o) ? ss[t - o] : 0;
        __syncthreads();
        ss[t] += u;
        __syncthreads();
    }
    int run = lo + ss[t] - tsum;
    #pragma unroll
    for (int j = 0; j < 8; ++j) {
        const int key = 8 * t + j;
        cnt[key] = run;                  // becomes cursor
        if ((key & (NSLICE - 1)) == 0) {
            const int d = key >> 4;
            if (d < nd) rowptr[d0 + d] = run;
        }
        run += v[j];
    }
    __syncthreads();
    for (int idx = lo + t; idx < hiE; idx += 256) {
        const int2 e = binned[idx];
        const int src = e.x & 0x1FFFF;
        const int key = ((e.x >> 17) << 4) | (src >> 13);
        const int pos = atomicAdd(&cnt[key], 1);
        pairs[pos] = make_int2(src, e.y);
    }
}

// ============ SpMM1 full-row fp16 gather (+fused ReLU): wave per dst ========
__global__ __launch_bounds__(256) void spmm1_f16_kernel(
    const int* __restrict__ rowptr, const int2* __restrict__ pairs,
    const _Float16* __restrict__ h0, _Float16* __restrict__ h1)
{
    const int dst  = blockIdx.x * 4 + (threadIdx.x >> 6);
    const int lane = threadIdx.x & 63;
    if (dst >= NNODES) return;
    const int beg = rowptr[dst], end = rowptr[dst + 1];
    const _Float16* base = h0 + lane * 4;
    float a0[4] = {0.f, 0.f, 0.f, 0.f};
    float a1[4] = {0.f, 0.f, 0.f, 0.f};
    int j = beg;
    for (; j + 1 < end; j += 2) {
        const int2 p0 = pairs[j];
        const int2 p1 = pairs[j + 1];
        const half4 v0 = *(const half4*)(base + (size_t)p0.x * NHID);
        const half4 v1 = *(const half4*)(base + (size_t)p1.x * NHID);
        const float w0 = __int_as_float(p0.y), w1 = __int_as_float(p1.y);
        #pragma unroll
        for (int k = 0; k < 4; ++k) {
            a0[k] = fmaf((float)v0[k], w0, a0[k]);
            a1[k] = fmaf((float)v1[k], w1, a1[k]);
        }
    }
    if (j < end) {
        const int2 p0 = pairs[j];
        const half4 v0 = *(const half4*)(base + (size_t)p0.x * NHID);
        const float w0 = __int_as_float(p0.y);
        #pragma unroll
        for (int k = 0; k < 4; ++k)
            a0[k] = fmaf((float)v0[k], w0, a0[k]);
    }
    half4 o;
    o[0] = (_Float16)fmaxf(a0[0] + a1[0], 0.f);
    o[1] = (_Float16)fmaxf(a0[1] + a1[1], 0.f);
    o[2] = (_Float16)fmaxf(a0[2] + a1[2], 0.f);
    o[3] = (_Float16)fmaxf(a0[3] + a1[3], 0.f);
    *(half4*)(h1 + (size_t)dst * NHID + lane * 4) = o;
}

// ============ SpMM2 (fp16 gather) + fused log-softmax: wave per dst =========
__global__ __launch_bounds__(256) void spmm2_csr_kernel(
    const int* __restrict__ rowptr, const int2* __restrict__ pairs,
    const _Float16* __restrict__ h2, float* __restrict__ out)
{
    const int dst  = blockIdx.x * 4 + (threadIdx.x >> 6);
    const int lane = threadIdx.x & 63;
    if (dst >= NNODES) return;
    const int beg = rowptr[dst], end = rowptr[dst + 1];
    float a0 = 0.f, a1 = 0.f;
    int j = beg;
    for (; j + 1 < end; j += 2) {
        const int2 p0 = pairs[j];
        const int2 p1 = pairs[j + 1];
        float v0 = 0.f, v1 = 0.f;
        if (lane < NCLASS) {
            v0 = (float)h2[(size_t)p0.x * NCLASS + lane];
            v1 = (float)h2[(size_t)p1.x * NCLASS + lane];
        }
        a0 = fmaf(v0, __int_as_float(p0.y), a0);
        a1 = fmaf(v1, __int_as_float(p1.y), a1);
    }
    if (j < end) {
        const int2 p0 = pairs[j];
        float v0 = 0.f;
        if (lane < NCLASS) v0 = (float)h2[(size_t)p0.x * NCLASS + lane];
        a0 = fmaf(v0, __int_as_float(p0.y), a0);
    }
    const float acc = a0 + a1;
    float val = (lane < NCLASS) ? acc : -INFINITY;
    float m = val;
    #pragma unroll
    for (int o = 32; o >= 1; o >>= 1) m = fmaxf(m, __shfl_xor(m, o));
    float ex = (lane < NCLASS) ? expf(val - m) : 0.f;
    float s = ex;
    #pragma unroll
    for (int o = 32; o >= 1; o >>= 1) s += __shfl_xor(s, o);
    if (lane < NCLASS) out[(size_t)dst * NCLASS + lane] = val - m - logf(s);
}

// ============ launch ========================================================
extern "C" void kernel_launch(void* const* d_in, const int* in_sizes, int n_in,
                              void* d_out, int out_size, void* d_ws, size_t ws_size,
                              hipStream_t stream)
{
    const float* x  = (const float*)d_in[0];
    const int*   ei = (const int*)d_in[1];   // [2,E]: dst row then src row
    const float* ew = (const float*)d_in[2];
    const float* W1 = (const float*)d_in[3];
    const float* b1 = (const float*)d_in[4];
    const float* W2 = (const float*)d_in[5];
    const float* b2 = (const float*)d_in[6];
    float* out = (float*)d_out;

    char* ws = (char*)d_ws;
    const size_t H_BYTES = (size_t)NNODES * NHID * 4;        // 102,400,000
    _Float16* h0 = (_Float16*)(ws);          // 51.2 MB fp16
    _Float16* h1 = (_Float16*)(ws + H_BYTES);// 51.2 MB fp16
    int2* binned = (int2*)(ws + H_BYTES);    // aliases h1 (dead before spmm1)
    int2* pairs  = (int2*)(ws + 2 * H_BYTES);                // 25.6 MB
    char* region = ws + 2 * H_BYTES + (size_t)NEDGES * 8;
    // W1T (256 KB) dead after gemm1; CSR arrays occupy the same bytes after.
    _Float16* W1T = (_Float16*)(region);                     // 262,144 B
    int* rowptr = (int*)(region);                            // 400,016 B
    int* bhist  = (int*)(region + 400016);                   // 3,128 B
    int* bbase  = (int*)(region + 403152);                   // 3,132 B
    int* bcur   = (int*)(region + 406288);                   // 3,128 B
    _Float16* h2 = (_Float16*)(ws);    // 8 MB fp16, aliases h0 (dead after spmm1)

    // 1. W1 -> transposed fp16; h0 = fp16(x @ W1 + b1) single-pass f16 MFMA
    w1_f16_kernel<<<(NFEAT * NHID + 255) / 256, 256, 0, stream>>>(W1, W1T);
    gemm1_f16_kernel<<<(NNODES + 63) / 64, 256, 0, stream>>>(x, W1T, b1, h0);
    // 2. CSR build: binned counting sort (W1T dead from here)
    csr_init_kernel<<<(NBUCK + 255) / 256, 256, 0, stream>>>(bhist, rowptr);
    bin_count_kernel<<<NTILE, 256, 0, stream>>>(ei, bhist);
    bucket_scan_kernel<<<1, 1024, 0, stream>>>(bhist, bbase, bcur);
    bin_scatter_kernel<<<NTILE, 256, 0, stream>>>(ei, ew, bcur, binned);
    regroup_kernel<<<NBUCK, 256, 0, stream>>>(bbase, binned, rowptr, pairs);
    // 3. h1 = fp16(relu(spmm(h0))) — full-row gather, src-slice-ordered
    spmm1_f16_kernel<<<(NNODES + 3) / 4, 256, 0, stream>>>(rowptr, pairs, h0, h1);
    // 4. h2 = fp16(h1 @ W2 + b2)
    gemm2_kernel<<<(NNODES + 63) / 64, 256, 0, stream>>>(h1, W2, b2, h2);
    // 5. out = logsoftmax(spmm(h2)) — fp16 gather
    spmm2_csr_kernel<<<(NNODES + 3) / 4, 256, 0, stream>>>(rowptr, pairs, h2, out);
}